// Round 13
// baseline (179.239 us; speedup 1.0000x reference)
//
#include <hip/hip_runtime.h>
#include <hip/hip_fp16.h>

#define TSTEPS 4
#define DIM 32
#define BINW_SHIFT 8          // 256 nodes per coarse bin
#define NB 256                // scan width (actual bins = 196, rest zero)
#define HB 128                // histogram blocks in K1
#define GROWS 128             // GEMM rows per block
#define SP_CH 2048            // edges per split block
#define CAPB 4608             // max edges per bin (mean 4096, 8 sigma)
#define PAD_PER_BIN 772       // worst-case rec padding per bin (256*3 + 4)

// load 8 consecutive halfs (16B, aligned) -> two float4
__device__ __forceinline__ void ldx8h(const __half* p, float4& lo, float4& hi) {
    int4 u = *(const int4*)p;
    __half2* h = (__half2*)&u;
    float2 a = __half22float2(h[0]);
    float2 b = __half22float2(h[1]);
    float2 c = __half22float2(h[2]);
    float2 d = __half22float2(h[3]);
    lo = make_float4(a.x, a.y, b.x, b.y);
    hi = make_float4(c.x, c.y, d.x, d.y);
}

// ---- K1: per-block coarse histogram (blocks [0,HB)) + register-tiled GEMM ----
__global__ __launch_bounds__(256) void histxw_kernel(
    const int* __restrict__ ei, int* __restrict__ ghistPB, int* __restrict__ cursor,
    const float* __restrict__ s, const float* __restrict__ W, __half* __restrict__ xwp,
    int E, int rows, int N, int hch) {
    __shared__ float4 sW4[32][8];    // W[k][cg*4..+3]
    __shared__ float sS[GROWS][36];  // padded, float4-aligned
    __shared__ int lh[NB];
    int tid = threadIdx.x;
    if ((int)blockIdx.x < HB) {
        lh[tid] = 0;
        __syncthreads();
        int beg = blockIdx.x * hch;
        int end = min(beg + hch, E);
        for (int e = beg + tid; e < end; e += 256)
            atomicAdd(&lh[ei[E + e] >> BINW_SHIFT], 1);
        __syncthreads();
        ghistPB[blockIdx.x * NB + tid] = lh[tid];
        if (blockIdx.x == 0) cursor[tid] = 0;
        return;
    }
    int row = tid >> 3;
    int cg = tid & 7;
    sW4[row][cg] = ((const float4*)W)[tid];  // tid = k*8+cg exactly
    int rowBase = (blockIdx.x - HB) * GROWS;
#pragma unroll
    for (int j = 0; j < 4; j++) {
        int r = rowBase + row + j * 32;
        float4 sv = (r < rows) ? ((const float4*)s)[(size_t)r * 8 + cg]
                               : make_float4(0.f, 0.f, 0.f, 0.f);
        *(float4*)&sS[row + j * 32][cg * 4] = sv;
    }
    __syncthreads();
    float4 a0 = make_float4(0.f, 0.f, 0.f, 0.f);
    float4 a1 = a0, a2 = a0, a3 = a0;
#pragma unroll
    for (int k = 0; k < 32; k++) {
        float4 wv = sW4[k][cg];
        float s0 = sS[row][k];
        float s1 = sS[row + 32][k];
        float s2 = sS[row + 64][k];
        float s3 = sS[row + 96][k];
        a0.x += s0 * wv.x; a0.y += s0 * wv.y; a0.z += s0 * wv.z; a0.w += s0 * wv.w;
        a1.x += s1 * wv.x; a1.y += s1 * wv.y; a1.z += s1 * wv.z; a1.w += s1 * wv.w;
        a2.x += s2 * wv.x; a2.y += s2 * wv.y; a2.z += s2 * wv.z; a2.w += s2 * wv.w;
        a3.x += s3 * wv.x; a3.y += s3 * wv.y; a3.z += s3 * wv.z; a3.w += s3 * wv.w;
    }
    float4 accs[4] = {a0, a1, a2, a3};
#pragma unroll
    for (int j = 0; j < 4; j++) {
        int r = rowBase + row + j * 32;
        if (r < rows) {
            int t = r / N;
            int n = r - t * N;
            __half2 h0 = __floats2half2_rn(accs[j].x, accs[j].y);
            __half2 h1 = __floats2half2_rn(accs[j].z, accs[j].w);
            uint2 u;
            u.x = *(unsigned int*)&h0;
            u.y = *(unsigned int*)&h1;
            *(uint2*)(xwp + (size_t)n * 128 + t * 32 + cg * 4) = u;
        }
    }
}

// ---- K2: multisplit (R10-proven) ----
__global__ __launch_bounds__(256) void split_kernel(
    const int* __restrict__ ei, const int* __restrict__ ghistPB,
    int* __restrict__ cursor, int2* __restrict__ esorted, int E) {
    __shared__ int phw[4][NB];
    __shared__ int sBS[NB], pscan[NB], gb[NB], pcur[NB];
    __shared__ int2 sbuf[SP_CH];
    int tid = threadIdx.x;
    int gv = 0;
    for (int r = 0; r < HB; r++) gv += ghistPB[r * NB + tid];
    sBS[tid] = gv;
    __syncthreads();
    for (int off = 1; off < 256; off <<= 1) {
        int t = (tid >= off) ? sBS[tid - off] : 0;
        __syncthreads();
        sBS[tid] += t;
        __syncthreads();
    }
    int binStart = sBS[tid] - gv;
    phw[0][tid] = 0; phw[1][tid] = 0; phw[2][tid] = 0; phw[3][tid] = 0;
    __syncthreads();
    int beg = blockIdx.x * SP_CH;
    int end = min(beg + SP_CH, E);
    int cnt = end - beg;
    int wv = tid >> 6;
    for (int e = beg + tid; e < end; e += 256)
        atomicAdd(&phw[wv][ei[E + e] >> BINW_SHIFT], 1);
    __syncthreads();
    int v = phw[0][tid] + phw[1][tid] + phw[2][tid] + phw[3][tid];
    pscan[tid] = v;
    __syncthreads();
    for (int off = 1; off < 256; off <<= 1) {
        int t = (tid >= off) ? pscan[tid - off] : 0;
        __syncthreads();
        pscan[tid] += t;
        __syncthreads();
    }
    pscan[tid] -= v;
    pcur[tid] = pscan[tid];
    gb[tid] = v ? (binStart + atomicAdd(&cursor[tid], v)) : 0;
    __syncthreads();
    for (int e = beg + tid; e < end; e += 256) {
        int2 r;
        r.x = ei[e];
        r.y = ei[E + e];
        int b = r.y >> BINW_SHIFT;
        int p = atomicAdd(&pcur[b], 1);
        sbuf[p] = r;
    }
    __syncthreads();
    for (int idx = tid; idx < cnt; idx += 256) {
        int2 e = sbuf[idx];
        int b = e.y >> BINW_SHIFT;
        esorted[gb[b] + (idx - pscan[b])] = e;
    }
}

// ---- K3: per-bin exact CSR (R10-proven) ----
__global__ __launch_bounds__(256) void csr_kernel(
    const int* __restrict__ ghistPB, const int2* __restrict__ esorted,
    int* __restrict__ rec, int* __restrict__ offs, int* __restrict__ deg,
    float* __restrict__ dinv, int N) {
    __shared__ int sorted[CAPB + 768];
    __shared__ int sc[NB], lh[NB], loff[NB], lcur[NB];
    __shared__ int s_ebeg, s_cnt;
    int bin = blockIdx.x;
    int tid = threadIdx.x;
    int gv = 0;
    for (int r = 0; r < HB; r++) gv += ghistPB[r * NB + tid];
    sc[tid] = gv;
    __syncthreads();
    for (int off = 1; off < 256; off <<= 1) {
        int t = (tid >= off) ? sc[tid - off] : 0;
        __syncthreads();
        sc[tid] += t;
        __syncthreads();
    }
    if (tid == bin) { s_ebeg = sc[tid] - gv; s_cnt = gv; }
    __syncthreads();
    int ebeg = s_ebeg;
    int cnt = min(s_cnt, CAPB);
    int gbase = ((ebeg + 3) & ~3) + PAD_PER_BIN * bin;
    lh[tid] = 0;
    __syncthreads();
    for (int i = tid; i < cnt; i += 256)
        atomicAdd(&lh[esorted[ebeg + i].y & 255], 1);
    __syncthreads();
    int padded = (lh[tid] + 3) & ~3;
    sc[tid] = padded;
    __syncthreads();
    for (int off = 1; off < 256; off <<= 1) {
        int t = (tid >= off) ? sc[tid - off] : 0;
        __syncthreads();
        sc[tid] += t;
        __syncthreads();
    }
    loff[tid] = sc[tid] - padded;
    lcur[tid] = 0;
    __syncthreads();
    int run = sc[255];
    for (int i = tid; i < run; i += 256) sorted[i] = 0;
    __syncthreads();
    for (int i = tid; i < cnt; i += 256) {
        int2 e = esorted[ebeg + i];
        int ln = e.y & 255;
        int p = atomicAdd(&lcur[ln], 1);
        sorted[loff[ln] + p] = e.x;
    }
    __syncthreads();
    for (int i = tid; i < run; i += 256) rec[gbase + i] = sorted[i];
    int n = (bin << BINW_SHIFT) + tid;
    if (n < N) {
        offs[n] = gbase + loff[tid];
        deg[n] = lh[tid];
        dinv[n] = rsqrtf((float)lh[tid] + 1.0f);
    }
}

// ---- K4: fused gather, 16 lanes/node, int4 (16B) loads, unroll-8 ----
// lane g in [0,16): t = g>>2, cols (g&3)*8..+8. Doubles bytes-in-flight per
// thread vs the 32-lane/8B version (latency-bound loop).
__global__ __launch_bounds__(256) void gather_kernel(
    const int* __restrict__ rec, const int* __restrict__ offs,
    const int* __restrict__ deg, const __half* __restrict__ xwp,
    const float* __restrict__ dinv, const float* __restrict__ z,
    float* __restrict__ out, int N) {
    int gid = blockIdx.x * 256 + threadIdx.x;
    int n = gid >> 4;
    if (n >= N) return;
    int wl = threadIdx.x & 63;
    int grp = wl >> 4;       // node-in-wave (0..3)
    int g = wl & 15;
    long lofs = g * 8;       // offset in halfs (16B per lane)

    float dn = dinv[n];
    int beg = offs[n];       // multiple of 4 -> int4-aligned
    int cntn = deg[n];

    float4 aLo = make_float4(0.f, 0.f, 0.f, 0.f);
    float4 aHi = aLo;
    int i = 0;
    for (; i + 8 <= cntn; i += 8) {
        int4 sa = *(const int4*)(rec + beg + i);
        int4 sb = *(const int4*)(rec + beg + i + 4);
        float n0 = dinv[sa.x] * dn, n1 = dinv[sa.y] * dn;
        float n2 = dinv[sa.z] * dn, n3 = dinv[sa.w] * dn;
        float n4 = dinv[sb.x] * dn, n5 = dinv[sb.y] * dn;
        float n6 = dinv[sb.z] * dn, n7 = dinv[sb.w] * dn;
        float4 l0, h0, l1, h1, l2, h2, l3, h3, l4, h4, l5, h5, l6, h6, l7, h7;
        ldx8h(xwp + (long)sa.x * 128 + lofs, l0, h0);
        ldx8h(xwp + (long)sa.y * 128 + lofs, l1, h1);
        ldx8h(xwp + (long)sa.z * 128 + lofs, l2, h2);
        ldx8h(xwp + (long)sa.w * 128 + lofs, l3, h3);
        ldx8h(xwp + (long)sb.x * 128 + lofs, l4, h4);
        ldx8h(xwp + (long)sb.y * 128 + lofs, l5, h5);
        ldx8h(xwp + (long)sb.z * 128 + lofs, l6, h6);
        ldx8h(xwp + (long)sb.w * 128 + lofs, l7, h7);
        aLo.x += n0 * l0.x + n1 * l1.x + n2 * l2.x + n3 * l3.x
               + n4 * l4.x + n5 * l5.x + n6 * l6.x + n7 * l7.x;
        aLo.y += n0 * l0.y + n1 * l1.y + n2 * l2.y + n3 * l3.y
               + n4 * l4.y + n5 * l5.y + n6 * l6.y + n7 * l7.y;
        aLo.z += n0 * l0.z + n1 * l1.z + n2 * l2.z + n3 * l3.z
               + n4 * l4.z + n5 * l5.z + n6 * l6.z + n7 * l7.z;
        aLo.w += n0 * l0.w + n1 * l1.w + n2 * l2.w + n3 * l3.w
               + n4 * l4.w + n5 * l5.w + n6 * l6.w + n7 * l7.w;
        aHi.x += n0 * h0.x + n1 * h1.x + n2 * h2.x + n3 * h3.x
               + n4 * h4.x + n5 * h5.x + n6 * h6.x + n7 * h7.x;
        aHi.y += n0 * h0.y + n1 * h1.y + n2 * h2.y + n3 * h3.y
               + n4 * h4.y + n5 * h5.y + n6 * h6.y + n7 * h7.y;
        aHi.z += n0 * h0.z + n1 * h1.z + n2 * h2.z + n3 * h3.z
               + n4 * h4.z + n5 * h5.z + n6 * h6.z + n7 * h7.z;
        aHi.w += n0 * h0.w + n1 * h1.w + n2 * h2.w + n3 * h3.w
               + n4 * h4.w + n5 * h5.w + n6 * h6.w + n7 * h7.w;
    }
    for (; i < cntn; i += 4) {
        int4 s4 = *(const int4*)(rec + beg + i);
        int rem = cntn - i;
        int i0 = s4.x;
        int i1 = (rem > 1) ? s4.y : i0;
        int i2 = (rem > 2) ? s4.z : i0;
        int i3 = (rem > 3) ? s4.w : i0;
        float n0 = dinv[i0] * dn;
        float n1 = (rem > 1) ? dinv[i1] * dn : 0.f;
        float n2 = (rem > 2) ? dinv[i2] * dn : 0.f;
        float n3 = (rem > 3) ? dinv[i3] * dn : 0.f;
        float4 l0, h0, l1, h1, l2, h2, l3, h3;
        ldx8h(xwp + (long)i0 * 128 + lofs, l0, h0);
        ldx8h(xwp + (long)i1 * 128 + lofs, l1, h1);
        ldx8h(xwp + (long)i2 * 128 + lofs, l2, h2);
        ldx8h(xwp + (long)i3 * 128 + lofs, l3, h3);
        aLo.x += n0 * l0.x + n1 * l1.x + n2 * l2.x + n3 * l3.x;
        aLo.y += n0 * l0.y + n1 * l1.y + n2 * l2.y + n3 * l3.y;
        aLo.z += n0 * l0.z + n1 * l1.z + n2 * l2.z + n3 * l3.z;
        aLo.w += n0 * l0.w + n1 * l1.w + n2 * l2.w + n3 * l3.w;
        aHi.x += n0 * h0.x + n1 * h1.x + n2 * h2.x + n3 * h3.x;
        aHi.y += n0 * h0.y + n1 * h1.y + n2 * h2.y + n3 * h3.y;
        aHi.z += n0 * h0.z + n1 * h1.z + n2 * h2.z + n3 * h3.z;
        aHi.w += n0 * h0.w + n1 * h1.w + n2 * h2.w + n3 * h3.w;
    }
    // self loop
    {
        float d2 = dn * dn;
        float4 ls, hs;
        ldx8h(xwp + (long)n * 128 + lofs, ls, hs);
        aLo.x += d2 * ls.x; aLo.y += d2 * ls.y; aLo.z += d2 * ls.z; aLo.w += d2 * ls.w;
        aHi.x += d2 * hs.x; aHi.y += d2 * hs.y; aHi.z += d2 * hs.z; aHi.w += d2 * hs.w;
    }
    // transpose: lane (grp,g) holds (t=g>>2, cg=g&3). Gather xs[t] for cg=g
    // from lanes grp*16 + t*4 + g (valid for g<4; others produce don't-cares).
    float4 xLo[TSTEPS], xHi[TSTEPS];
#pragma unroll
    for (int t = 0; t < TSTEPS; t++) {
        int srcLane = grp * 16 + t * 4 + (g & 3);
        xLo[t].x = __shfl(aLo.x, srcLane, 64);
        xLo[t].y = __shfl(aLo.y, srcLane, 64);
        xLo[t].z = __shfl(aLo.z, srcLane, 64);
        xLo[t].w = __shfl(aLo.w, srcLane, 64);
        xHi[t].x = __shfl(aHi.x, srcLane, 64);
        xHi[t].y = __shfl(aHi.y, srcLane, 64);
        xHi[t].z = __shfl(aHi.z, srcLane, 64);
        xHi[t].w = __shfl(aHi.w, srcLane, 64);
    }
    if (g < 4) {
        float4 yLo, yHi;
        yLo.x = (xLo[0].x + xLo[1].x + xLo[2].x + xLo[3].x) * 0.25f;
        yLo.y = (xLo[0].y + xLo[1].y + xLo[2].y + xLo[3].y) * 0.25f;
        yLo.z = (xLo[0].z + xLo[1].z + xLo[2].z + xLo[3].z) * 0.25f;
        yLo.w = (xLo[0].w + xLo[1].w + xLo[2].w + xLo[3].w) * 0.25f;
        yHi.x = (xHi[0].x + xHi[1].x + xHi[2].x + xHi[3].x) * 0.25f;
        yHi.y = (xHi[0].y + xHi[1].y + xHi[2].y + xHi[3].y) * 0.25f;
        yHi.z = (xHi[0].z + xHi[1].z + xHi[2].z + xHi[3].z) * 0.25f;
        yHi.w = (xHi[0].w + xHi[1].w + xHi[2].w + xHi[3].w) * 0.25f;
        float4 vLo = make_float4(0.f, 0.f, 0.f, 0.f);
        float4 vHi = vLo;
        int colBase = n * 32 + g * 8;
#pragma unroll
        for (int t = 0; t < TSTEPS; t++) {
            float4 oLo, oHi;
            vLo.x += xLo[t].x; oLo.x = (vLo.x >= 1.0f) ? 1.0f : 0.0f; vLo.x -= oLo.x;
            vLo.y += xLo[t].y; oLo.y = (vLo.y >= 1.0f) ? 1.0f : 0.0f; vLo.y -= oLo.y;
            vLo.z += xLo[t].z; oLo.z = (vLo.z >= 1.0f) ? 1.0f : 0.0f; vLo.z -= oLo.z;
            vLo.w += xLo[t].w; oLo.w = (vLo.w >= 1.0f) ? 1.0f : 0.0f; vLo.w -= oLo.w;
            vHi.x += xHi[t].x; oHi.x = (vHi.x >= 1.0f) ? 1.0f : 0.0f; vHi.x -= oHi.x;
            vHi.y += xHi[t].y; oHi.y = (vHi.y >= 1.0f) ? 1.0f : 0.0f; vHi.y -= oHi.y;
            vHi.z += xHi[t].z; oHi.z = (vHi.z >= 1.0f) ? 1.0f : 0.0f; vHi.z -= oHi.z;
            vHi.w += xHi[t].w; oHi.w = (vHi.w >= 1.0f) ? 1.0f : 0.0f; vHi.w -= oHi.w;
            *(float4*)(out + (size_t)t * N * 32 + colBase) = oLo;
            *(float4*)(out + (size_t)t * N * 32 + colBase + 4) = oHi;
        }
        float4 zLo = *(const float4*)(z + colBase);
        float4 zHi = *(const float4*)(z + colBase + 4);
        float4 znLo, znHi;
        znLo.x = zLo.x + yLo.x; znLo.y = zLo.y + yLo.y;
        znLo.z = zLo.z + yLo.z; znLo.w = zLo.w + yLo.w;
        znHi.x = zHi.x + yHi.x; znHi.y = zHi.y + yHi.y;
        znHi.z = zHi.z + yHi.z; znHi.w = zHi.w + yHi.w;
        *(float4*)(out + (size_t)TSTEPS * N * 32 + colBase) = znLo;
        *(float4*)(out + (size_t)TSTEPS * N * 32 + colBase + 4) = znHi;
    }
}

extern "C" void kernel_launch(void* const* d_in, const int* in_sizes, int n_in,
                              void* d_out, int out_size, void* d_ws, size_t ws_size,
                              hipStream_t stream) {
    const float* s_seq = (const float*)d_in[0];
    const float* z_seq = (const float*)d_in[1];
    const float* W     = (const float*)d_in[2];
    const int*   ei    = (const int*)d_in[3];
    float* out = (float*)d_out;

    int N = in_sizes[1] / DIM;   // 50000
    int E = in_sizes[3] / 2;     // 800000
    int rows = TSTEPS * N;       // 200000
    int nb = (N + 255) >> BINW_SHIFT;        // 196
    int nchunks = (E + SP_CH - 1) / SP_CH;   // 391

    // ws layout: xwp(fp16) | esorted | rec | offs | deg | dinv | ghistPB | cursor
    char* w = (char*)d_ws;
    __half* xwp     = (__half*)w; w += (size_t)rows * DIM * 2;            // 12.8 MB
    int2*  esorted  = (int2*)w;   w += (size_t)E * 8;                     // 6.4 MB
    int*   rec      = (int*)w;    w += ((size_t)E + PAD_PER_BIN * nb + 16) * 4;
    int*   offs     = (int*)w;    w += (size_t)N * 4;
    int*   deg      = (int*)w;    w += (size_t)N * 4;
    float* dinv     = (float*)w;  w += (size_t)N * 4;
    int*   ghistPB  = (int*)w;    w += (size_t)HB * NB * 4;               // 128 KB
    int*   cursor   = (int*)w;    w += NB * 4;

    int hch = (E + HB - 1) / HB;
    int xwBlocks = (rows + GROWS - 1) / GROWS;   // 1563
    histxw_kernel<<<HB + xwBlocks, 256, 0, stream>>>(ei, ghistPB, cursor, s_seq, W,
                                                     xwp, E, rows, N, hch);
    split_kernel<<<nchunks, 256, 0, stream>>>(ei, ghistPB, cursor, esorted, E);
    csr_kernel<<<nb, 256, 0, stream>>>(ghistPB, esorted, rec, offs, deg, dinv, N);
    gather_kernel<<<(N * 16 + 255) / 256, 256, 0, stream>>>(rec, offs, deg, xwp,
                                                            dinv, z_seq, out, N);
}